// Round 16
// baseline (763.036 us; speedup 1.0000x reference)
//
#include <hip/hip_runtime.h>
#include <hip/hip_bf16.h>
#include <stdint.h>

// Problem dims
#define B_SZ 32
#define T_SZ 512
#define I_SZ 1024
#define H_SZ 8
#define HS_SZ 128

typedef __attribute__((ext_vector_type(8))) short short8;
typedef __attribute__((ext_vector_type(4))) float f32x4;

// ---------------- fp32 <-> bf16 helpers ----------------
static __device__ __forceinline__ unsigned short f2bf(float f) {
  union { float f; unsigned int u; } c; c.f = f;
  unsigned int u = c.u;
  unsigned int r = (u + 0x7fffu + ((u >> 16) & 1u)) >> 16;
  return (unsigned short)r;
}
static __device__ __forceinline__ float bf2f(unsigned short s) {
  union { unsigned int u; float f; } c; c.u = ((unsigned int)s) << 16;
  return c.f;
}
static __device__ __forceinline__ void split2(float x, unsigned short& hi,
                                              unsigned short& lo) {
  hi = f2bf(x);
  lo = f2bf(x - bf2f(hi));
}

// ---------------- fused conversion (round 16: one launch) ----------------
// blocks [0,16384): xs -> Ahi/Alo (4194304 float4s)
// blocks [16384,20480): wif/wzo -> Whi/Wlo combined-layout (1048576 float4s)
__global__ void conv_all(const float* __restrict__ x,
                         const float* __restrict__ wif,
                         const float* __restrict__ wzo,
                         unsigned short* __restrict__ xhi,
                         unsigned short* __restrict__ xlo,
                         unsigned short* __restrict__ whi,
                         unsigned short* __restrict__ wlo) {
  int bid = blockIdx.x;
  if (bid < 16384) {
    int i = bid * 256 + threadIdx.x;
    float4 v = ((const float4*)x)[i];
    ushort4 h, l;
    split2(v.x, h.x, l.x);
    split2(v.y, h.y, l.y);
    split2(v.z, h.z, l.z);
    split2(v.w, h.w, l.w);
    ((ushort4*)xhi)[i] = h;
    ((ushort4*)xlo)[i] = l;
  } else {
    int i = (bid - 16384) * 256 + threadIdx.x;  // float4 index
    int flat = i * 4;
    int n = flat >> 10;
    int col = flat & 1023;
    int h = n >> 9, k4 = n & 511;
    const float* src =
        (k4 < 256) ? (wif + ((size_t)(h * 256 + k4) * 1024 + col))
                   : (wzo + ((size_t)(h * 256 + (k4 - 256)) * 1024 + col));
    float4 v = *(const float4*)src;
    ushort4 hh, ll;
    split2(v.x, hh.x, ll.x);
    split2(v.y, hh.y, ll.y);
    split2(v.z, hh.z, ll.z);
    split2(v.w, hh.w, ll.w);
    ((ushort4*)whi)[i] = hh;
    ((ushort4*)wlo)[i] = ll;
  }
}

// ---------------- GEMM v4.1 (round 16): per-mi read/MFMA interleave -------
// 256x256 tile, BK=32, 8 waves (2M x 4N), 2x64KB LDS dbuf, counted vmcnt,
// raw s_barrier, slot-XOR swizzle, setprio, 3-pass split-bf16.
// Round-16 change: pass 1 reads ah[mi] immediately before its 4 MFMAs
// (was: 12-read burst before any MFMA -> LDS pipe starves the matrix pipe
// at K-step start). Compiler's counted lgkmcnt gives 1-ahead pipelining.
__device__ __forceinline__ void gld_lds16(const void* g, void* l) {
  __builtin_amdgcn_global_load_lds(
      (const __attribute__((address_space(1))) void*)g,
      (__attribute__((address_space(3))) void*)l, 16, 0, 0);
}

__global__ __launch_bounds__(512)
void gemm3_kernel(const unsigned short* __restrict__ Ahi,
                  const unsigned short* __restrict__ Alo,
                  const unsigned short* __restrict__ Whi,
                  const unsigned short* __restrict__ Wlo,
                  float* __restrict__ G, int t0, int toff, int S, int lw) {
  __shared__ short lds2[2][32768];  // 2 x 64 KB
  // per-buffer layout (shorts): AH @0, AL @8192, WH @16384, WL @24576

  const int tid = threadIdx.x;
  const int lane = tid & 63, wv = tid >> 6;
  const int wm = wv >> 2, wn = wv & 3;   // 2 M-waves x 4 N-waves
  const int bx = blockIdx.x, by = blockIdx.y;
  const int l15 = lane & 15, kg = lane >> 4;
  const int wmask = (1 << lw) - 1;

  const unsigned short* gsrc[8];
  int ldst[8];
#pragma unroll
  for (int t = 0; t < 4; ++t)
#pragma unroll
    for (int k = 0; k < 2; ++k) {
      int u = k * 512 + tid;       // 0..1023
      int r = u >> 2, j = u & 3;   // row 0..255, 16B unit in row
      int gslot = j ^ ((r >> 1) & 3);
      if (t < 2) {
        int cr = bx * 256 + r;
        size_t xsrow = (size_t)(cr >> lw) * 512 + t0 + (cr & wmask);
        gsrc[t * 2 + k] = ((t == 0) ? Ahi : Alo) + xsrow * 1024 + gslot * 8;
      } else {
        size_t wr = (size_t)by * 256 + r;
        gsrc[t * 2 + k] = ((t == 2) ? Whi : Wlo) + wr * 1024 + gslot * 8;
      }
      ldst[t * 2 + k] = t * 8192 + (k * 512 + wv * 64) * 8;
    }

  int offa[8], offw[4];
#pragma unroll
  for (int mi = 0; mi < 8; ++mi) {
    int r = wm * 128 + mi * 16 + l15;
    offa[mi] = r * 32 + (kg ^ ((r >> 1) & 3)) * 8;
  }
#pragma unroll
  for (int ni = 0; ni < 4; ++ni) {
    int r = wn * 64 + ni * 16 + l15;
    offw[ni] = r * 32 + (kg ^ ((r >> 1) & 3)) * 8;
  }

  f32x4 zero4 = {0.f, 0.f, 0.f, 0.f};
  f32x4 acc[8][4];
#pragma unroll
  for (int mi = 0; mi < 8; ++mi)
#pragma unroll
    for (int ni = 0; ni < 4; ++ni) acc[mi][ni] = zero4;

#pragma unroll
  for (int s8 = 0; s8 < 8; ++s8) gld_lds16(gsrc[s8], &lds2[0][ldst[s8]]);
#pragma unroll
  for (int s8 = 0; s8 < 8; ++s8)
    gld_lds16(gsrc[s8] + 32, &lds2[1][ldst[s8]]);
  asm volatile("s_waitcnt vmcnt(8)" : : : "memory");
  __builtin_amdgcn_s_barrier();

  for (int ks = 0; ks < 32; ++ks) {
    const short* bp = &lds2[ks & 1][0];

    short8 ah[8], wh4[4], wl4[4];
#pragma unroll
    for (int ni = 0; ni < 4; ++ni)
      wh4[ni] = *(const short8*)(bp + 16384 + offw[ni]);

    __builtin_amdgcn_s_setprio(1);
    // pass 1: hi*hi — ah[mi] read immediately before its MFMAs (interleave)
#pragma unroll
    for (int mi = 0; mi < 8; ++mi) {
      ah[mi] = *(const short8*)(bp + offa[mi]);
#pragma unroll
      for (int ni = 0; ni < 4; ++ni)
        acc[mi][ni] = __builtin_amdgcn_mfma_f32_16x16x32_bf16(
            ah[mi], wh4[ni], acc[mi][ni], 0, 0, 0);
    }
    // pass 2: lo*hi (al transient, read-use-die)
#pragma unroll
    for (int mi = 0; mi < 8; ++mi) {
      short8 al = *(const short8*)(bp + 8192 + offa[mi]);
#pragma unroll
      for (int ni = 0; ni < 4; ++ni)
        acc[mi][ni] = __builtin_amdgcn_mfma_f32_16x16x32_bf16(
            al, wh4[ni], acc[mi][ni], 0, 0, 0);
    }
    // pass 3: hi*lo
#pragma unroll
    for (int ni = 0; ni < 4; ++ni)
      wl4[ni] = *(const short8*)(bp + 24576 + offw[ni]);
#pragma unroll
    for (int mi = 0; mi < 8; ++mi)
#pragma unroll
      for (int ni = 0; ni < 4; ++ni)
        acc[mi][ni] = __builtin_amdgcn_mfma_f32_16x16x32_bf16(
            ah[mi], wl4[ni], acc[mi][ni], 0, 0, 0);
    __builtin_amdgcn_s_setprio(0);

    asm volatile("s_waitcnt lgkmcnt(0)" : : : "memory");
    __builtin_amdgcn_sched_barrier(0);
    __builtin_amdgcn_s_barrier();  // buf[ks&1] free to overwrite

    if (ks + 2 < 32) {
#pragma unroll
      for (int s8 = 0; s8 < 8; ++s8)
        gld_lds16(gsrc[s8] + (ks + 2) * 32, &lds2[ks & 1][ldst[s8]]);
      asm volatile("s_waitcnt vmcnt(8)" : : : "memory");
    } else {
      asm volatile("s_waitcnt vmcnt(0)" : : : "memory");
    }
    __builtin_amdgcn_s_barrier();  // buf[(ks+1)&1] ready for all waves
  }

  // epilogue: C/D layout (m89): col = lane&15, row = (lane>>4)*4+reg.
  // window row -> super-chunk row: b*S + toff + m
#pragma unroll
  for (int mi = 0; mi < 8; ++mi)
#pragma unroll
    for (int ni = 0; ni < 4; ++ni)
#pragma unroll
      for (int r = 0; r < 4; ++r) {
        int cr = bx * 256 + wm * 128 + mi * 16 + kg * 4 + r;
        int b = cr >> lw, m = cr & wmask;
        size_t growo = (size_t)b * S + toff + m;
        int gcol = by * 256 + wn * 64 + ni * 16 + l15;
        G[growo * 4096 + gcol] = acc[mi][ni][r];
      }
}

// ---------------- Recurrence (round 16) ----------------
// Round-12 structure (scalar v_fmac matvec on resident weights, readlane
// h-broadcast, stride-20 b128 exchange, raw lgkm-only barrier, 1/step).
// Round-16 changes:
//  (i)  bias+G folded into the q==0 partials: waves 0-1 add bias[row]+G[row]
//       into a0..a3 during matvec (em-indexed); waves 2-7 skip ALL G loads
//       and addressing (wave-uniform branch). Gate drops 8 adds/thread.
//  (ii) sched_barrier(0) removed (gate reads are ordinary loads behind a
//       memory-clobbered asm barrier; rule-18 hazard doesn't apply).
__global__ __launch_bounds__(512, 1)
void recur_kernel(const float* __restrict__ G,     // [32*tch, 4096] chunk
                  const float* __restrict__ Whh,   // [8,512,128]
                  const float* __restrict__ bias,  // [8,512]
                  float* __restrict__ out,         // [32,512,1024]
                  float* __restrict__ state,       // 4 x [32,8,128]
                  int t0, int tch, int first) {
  int blk = blockIdx.x;
  int b = blk >> 3, h = blk & 7;
  int t = threadIdx.x;
  int w = t >> 6;             // wave 0..7
  int l = t & 63;             // lane
  int q = w >> 1;             // col-slice / pair 0..3
  int em = (w & 1) * 64 + l;  // matvec output element 0..127
  int eg = q * 32 + (l & 31); // gate element this thread maintains
  bool gq0 = (q == 0);        // pair 0 folds bias+G into its partials

  __shared__ __align__(16) float part[2][128 * 20];  // 20 KB

  // weights: wreg[g*32+c] = Whh[h][g*128+em][32q+c]
  float wreg[128];
  {
    const float* wb = Whh + (size_t)h * 65536 + (size_t)q * 32;
#pragma unroll
    for (int g = 0; g < 4; ++g) {
      const float4* wp = (const float4*)(wb + (size_t)(g * 128 + em) * 128);
#pragma unroll
      for (int c4 = 0; c4 < 8; ++c4) {
        float4 v = wp[c4];
        wreg[g * 32 + c4 * 4 + 0] = v.x;
        wreg[g * 32 + c4 * 4 + 1] = v.y;
        wreg[g * 32 + c4 * 4 + 2] = v.z;
        wreg[g * 32 + c4 * 4 + 3] = v.w;
      }
    }
  }
#pragma unroll
  for (int i = 0; i < 128; ++i)
    asm volatile("" : "+v"(wreg[i]));  // opaque def: keep resident

  int si = (b * 8 + h) * 128 + eg;
  float hreg = 0.f, c_r = 0.f, n_r = 0.f, m_r = 0.f;
  if (!first) {
    hreg = state[si];
    c_r = state[32768 + si];
    m_r = state[65536 + si];
    n_r = state[98304 + si];
  }

  // matvec-side bias + G (em-indexed), used only by waves 0-1
  float bm0 = 0.f, bm1 = 0.f, bm2 = 0.f, bm3 = 0.f;
  float g0 = 0.f, g1 = 0.f, g2 = 0.f, g3 = 0.f;
  const float* gpm = G + (size_t)(b * tch) * 4096 + h * 512 + em;
  if (gq0) {
    bm0 = bias[h * 512 + em];
    bm1 = bias[h * 512 + 128 + em];
    bm2 = bias[h * 512 + 256 + em];
    bm3 = bias[h * 512 + 384 + em];
    g0 = gpm[0];
    g1 = gpm[128];
    g2 = gpm[256];
    g3 = gpm[384];
  }

  float* op = out + ((size_t)b * 512 + t0) * 1024 + h * 128 + eg;
  bool writer = ((w & 1) == 0) && (l < 32);

  int ebase = em * 20 + q * 4;   // write slot
  int rb0 = eg * 20 + 0;
  int rb1 = eg * 20 + 4;
  int rb2 = eg * 20 + 8;
  int rb3 = eg * 20 + 12;

  for (int s = 0; s < tch; ++s) {
    // prefetch G(s+1) — waves 0-1 only (consumed at END of iteration s+1)
    float gn0 = 0.f, gn1 = 0.f, gn2 = 0.f, gn3 = 0.f;
    if (gq0 && s + 1 < tch) {
      const float* gr = gpm + (size_t)(s + 1) * 4096;
      gn0 = gr[0]; gn1 = gr[128]; gn2 = gr[256]; gn3 = gr[384];
    }

    // ---- matvec: h broadcast via readlane (VALU), no LDS ----
    float a0 = 0.f, a1 = 0.f, a2 = 0.f, a3 = 0.f;
    int hbits = __float_as_int(hreg);
#pragma unroll
    for (int c = 0; c < 32; ++c) {
      float hs = __int_as_float(__builtin_amdgcn_readlane(hbits, c));
      a0 = fmaf(wreg[c], hs, a0);
      a1 = fmaf(wreg[32 + c], hs, a1);
      a2 = fmaf(wreg[64 + c], hs, a2);
      a3 = fmaf(wreg[96 + c], hs, a3);
    }
    if (gq0) {  // fold bias + G(s) into pair-0 partials
      a0 += bm0 + g0;
      a1 += bm1 + g1;
      a2 += bm2 + g2;
      a3 += bm3 + g3;
    }
    float4 pv = {a0, a1, a2, a3};
    *(float4*)&part[s & 1][ebase] = pv;

    // barrier: only LDS must be visible across it (lgkm), NOT vmem
    asm volatile("s_waitcnt lgkmcnt(0)" : : : "memory");
    __builtin_amdgcn_s_barrier();

    // ---- gate: all waves, redundant per (lane-half x pair) ----
    float4 p0 = *(const float4*)&part[s & 1][rb0];  // includes bias+G
    float4 p1 = *(const float4*)&part[s & 1][rb1];
    float4 p2 = *(const float4*)&part[s & 1][rb2];
    float4 p3 = *(const float4*)&part[s & 1][rb3];
    float iv = (p0.x + p1.x) + (p2.x + p3.x);
    float fv = (p0.y + p1.y) + (p2.y + p3.y);
    float zv = (p0.z + p1.z) + (p2.z + p3.z);
    float ov = (p0.w + p1.w) + (p2.w + p3.w);
    float e2 = __expf(2.f * zv);
    float zt = 1.f - 2.f * __builtin_amdgcn_rcpf(e2 + 1.f);   // tanh
    float og = __builtin_amdgcn_rcpf(1.f + __expf(-ov));      // sigmoid
    float mn = fmaxf(fv + m_r, iv);
    float ie = __expf(iv - mn);
    float fe = __expf(fv + m_r - mn);
    c_r = fe * c_r + ie * zt;
    n_r = fe * n_r + ie;
    m_r = mn;
    float hnew = og * c_r * __builtin_amdgcn_rcpf(n_r);
    hreg = hnew;
    if (writer) op[(size_t)s * 1024] = hnew;
    if (gq0) { g0 = gn0; g1 = gn1; g2 = gn2; g3 = gn3; }
  }

  if (writer) {
    state[si] = hreg;
    state[32768 + si] = c_r;
    state[65536 + si] = m_r;
    state[98304 + si] = n_r;
  }
}

// ---------------- launch ----------------
extern "C" void kernel_launch(void* const* d_in, const int* in_sizes, int n_in,
                              void* d_out, int out_size, void* d_ws, size_t ws_size,
                              hipStream_t stream) {
  const float* xs   = (const float*)d_in[0];
  const float* wif  = (const float*)d_in[1];
  const float* wzo  = (const float*)d_in[2];
  const float* whh  = (const float*)d_in[3];
  const float* bias = (const float*)d_in[4];
  float* out = (float*)d_out;

  char* ws = (char*)d_ws;
  unsigned short* Ahi = (unsigned short*)ws;                 // 33,554,432 B
  unsigned short* Alo = (unsigned short*)(ws + 33554432);    // 33,554,432 B
  unsigned short* Whi = (unsigned short*)(ws + 67108864);    //  8,388,608 B
  unsigned short* Wlo = (unsigned short*)(ws + 75497472);    //  8,388,608 B
  const size_t gbase = 83886080;

  // Decoupled chunking:
  //   gemm window W = 128 steps  -> L3-resident working set
  //   recur super-chunk S = 256  -> fewer recur dispatches
  int S = 256;
  while (S > 8 && gbase + (size_t)32 * S * 4096 * 4 + 524288 > ws_size)
    S >>= 1;
  int W = (S < 128) ? S : 128;
  int lw = 0;
  while ((1 << (lw + 1)) <= W) ++lw;

  float* G = (float*)(ws + gbase);
  float* state = (float*)(ws + gbase + (size_t)32 * S * 4096 * 4);

  conv_all<<<20480, 256, 0, stream>>>(xs, wif, wzo, Ahi, Alo, Whi, Wlo);

  for (int t0 = 0; t0 < 512; t0 += S) {
    for (int tw = 0; tw < S; tw += W)
      gemm3_kernel<<<dim3((32 * W) / 256, 16), 512, 0, stream>>>(
          Ahi, Alo, Whi, Wlo, G, t0 + tw, tw, S, lw);
    recur_kernel<<<256, 512, 0, stream>>>(G, whh, bias, out, state, t0, S,
                                          t0 == 0);
  }
}

// Round 17
// 755.849 us; speedup vs baseline: 1.0095x; 1.0095x over previous
//
#include <hip/hip_runtime.h>
#include <hip/hip_bf16.h>
#include <stdint.h>

// Problem dims
#define B_SZ 32
#define T_SZ 512
#define I_SZ 1024
#define H_SZ 8
#define HS_SZ 128

typedef __attribute__((ext_vector_type(8))) short short8;
typedef __attribute__((ext_vector_type(4))) float f32x4;

// ---------------- fp32 <-> bf16 helpers ----------------
static __device__ __forceinline__ unsigned short f2bf(float f) {
  union { float f; unsigned int u; } c; c.f = f;
  unsigned int u = c.u;
  unsigned int r = (u + 0x7fffu + ((u >> 16) & 1u)) >> 16;
  return (unsigned short)r;
}
static __device__ __forceinline__ float bf2f(unsigned short s) {
  union { unsigned int u; float f; } c; c.u = ((unsigned int)s) << 16;
  return c.f;
}
static __device__ __forceinline__ void split2(float x, unsigned short& hi,
                                              unsigned short& lo) {
  hi = f2bf(x);
  lo = f2bf(x - bf2f(hi));
}

// ---------------- fused conversion (one launch; neutral vs split) --------
// blocks [0,16384): xs -> Ahi/Alo (4194304 float4s)
// blocks [16384,20480): wif/wzo -> Whi/Wlo combined-layout (1048576 float4s)
__global__ void conv_all(const float* __restrict__ x,
                         const float* __restrict__ wif,
                         const float* __restrict__ wzo,
                         unsigned short* __restrict__ xhi,
                         unsigned short* __restrict__ xlo,
                         unsigned short* __restrict__ whi,
                         unsigned short* __restrict__ wlo) {
  int bid = blockIdx.x;
  if (bid < 16384) {
    int i = bid * 256 + threadIdx.x;
    float4 v = ((const float4*)x)[i];
    ushort4 h, l;
    split2(v.x, h.x, l.x);
    split2(v.y, h.y, l.y);
    split2(v.z, h.z, l.z);
    split2(v.w, h.w, l.w);
    ((ushort4*)xhi)[i] = h;
    ((ushort4*)xlo)[i] = l;
  } else {
    int i = (bid - 16384) * 256 + threadIdx.x;  // float4 index
    int flat = i * 4;
    int n = flat >> 10;
    int col = flat & 1023;
    int h = n >> 9, k4 = n & 511;
    const float* src =
        (k4 < 256) ? (wif + ((size_t)(h * 256 + k4) * 1024 + col))
                   : (wzo + ((size_t)(h * 256 + (k4 - 256)) * 1024 + col));
    float4 v = *(const float4*)src;
    ushort4 hh, ll;
    split2(v.x, hh.x, ll.x);
    split2(v.y, hh.y, ll.y);
    split2(v.z, hh.z, ll.z);
    split2(v.w, hh.w, ll.w);
    ((ushort4*)whi)[i] = hh;
    ((ushort4*)wlo)[i] = ll;
  }
}

// ---------------- GEMM (round-15 measured-best: 256x256 tile) ------------
// 256x256 tile, BK=32, 8 waves (2M x 4N, wave-tile 128x64), 2x64KB LDS
// double-buffer, counted vmcnt (8 in flight, never 0 in steady state),
// raw s_barrier, slot-XOR swizzle, setprio, 3-pass split-bf16 (emulated
// fp32). Measured 73.5us/128-step window (~58% of MFMA ubench ceiling);
// round-16's per-mi read interleave was null -> reverted to this form.
__device__ __forceinline__ void gld_lds16(const void* g, void* l) {
  __builtin_amdgcn_global_load_lds(
      (const __attribute__((address_space(1))) void*)g,
      (__attribute__((address_space(3))) void*)l, 16, 0, 0);
}

__global__ __launch_bounds__(512)
void gemm3_kernel(const unsigned short* __restrict__ Ahi,
                  const unsigned short* __restrict__ Alo,
                  const unsigned short* __restrict__ Whi,
                  const unsigned short* __restrict__ Wlo,
                  float* __restrict__ G, int t0, int toff, int S, int lw) {
  __shared__ short lds2[2][32768];  // 2 x 64 KB
  // per-buffer layout (shorts): AH @0, AL @8192, WH @16384, WL @24576

  const int tid = threadIdx.x;
  const int lane = tid & 63, wv = tid >> 6;
  const int wm = wv >> 2, wn = wv & 3;   // 2 M-waves x 4 N-waves
  const int bx = blockIdx.x, by = blockIdx.y;
  const int l15 = lane & 15, kg = lane >> 4;
  const int wmask = (1 << lw) - 1;

  const unsigned short* gsrc[8];
  int ldst[8];
#pragma unroll
  for (int t = 0; t < 4; ++t)
#pragma unroll
    for (int k = 0; k < 2; ++k) {
      int u = k * 512 + tid;       // 0..1023
      int r = u >> 2, j = u & 3;   // row 0..255, 16B unit in row
      int gslot = j ^ ((r >> 1) & 3);
      if (t < 2) {
        int cr = bx * 256 + r;
        size_t xsrow = (size_t)(cr >> lw) * 512 + t0 + (cr & wmask);
        gsrc[t * 2 + k] = ((t == 0) ? Ahi : Alo) + xsrow * 1024 + gslot * 8;
      } else {
        size_t wr = (size_t)by * 256 + r;
        gsrc[t * 2 + k] = ((t == 2) ? Whi : Wlo) + wr * 1024 + gslot * 8;
      }
      ldst[t * 2 + k] = t * 8192 + (k * 512 + wv * 64) * 8;
    }

  int offa[8], offw[4];
#pragma unroll
  for (int mi = 0; mi < 8; ++mi) {
    int r = wm * 128 + mi * 16 + l15;
    offa[mi] = r * 32 + (kg ^ ((r >> 1) & 3)) * 8;
  }
#pragma unroll
  for (int ni = 0; ni < 4; ++ni) {
    int r = wn * 64 + ni * 16 + l15;
    offw[ni] = r * 32 + (kg ^ ((r >> 1) & 3)) * 8;
  }

  f32x4 zero4 = {0.f, 0.f, 0.f, 0.f};
  f32x4 acc[8][4];
#pragma unroll
  for (int mi = 0; mi < 8; ++mi)
#pragma unroll
    for (int ni = 0; ni < 4; ++ni) acc[mi][ni] = zero4;

#pragma unroll
  for (int s8 = 0; s8 < 8; ++s8) gld_lds16(gsrc[s8], &lds2[0][ldst[s8]]);
#pragma unroll
  for (int s8 = 0; s8 < 8; ++s8)
    gld_lds16(gsrc[s8] + 32, &lds2[1][ldst[s8]]);
  asm volatile("s_waitcnt vmcnt(8)" : : : "memory");
  __builtin_amdgcn_s_barrier();

  for (int ks = 0; ks < 32; ++ks) {
    const short* bp = &lds2[ks & 1][0];

    short8 ah[8], wh4[4], wl4[4];
#pragma unroll
    for (int mi = 0; mi < 8; ++mi) ah[mi] = *(const short8*)(bp + offa[mi]);
#pragma unroll
    for (int ni = 0; ni < 4; ++ni)
      wh4[ni] = *(const short8*)(bp + 16384 + offw[ni]);

    __builtin_amdgcn_s_setprio(1);
    // pass 1: hi*hi
#pragma unroll
    for (int mi = 0; mi < 8; ++mi)
#pragma unroll
      for (int ni = 0; ni < 4; ++ni)
        acc[mi][ni] = __builtin_amdgcn_mfma_f32_16x16x32_bf16(
            ah[mi], wh4[ni], acc[mi][ni], 0, 0, 0);
    // pass 2: lo*hi (al transient: read-use-die per mi, keeps regs low)
#pragma unroll
    for (int mi = 0; mi < 8; ++mi) {
      short8 al = *(const short8*)(bp + 8192 + offa[mi]);
#pragma unroll
      for (int ni = 0; ni < 4; ++ni)
        acc[mi][ni] = __builtin_amdgcn_mfma_f32_16x16x32_bf16(
            al, wh4[ni], acc[mi][ni], 0, 0, 0);
    }
    // pass 3: hi*lo
#pragma unroll
    for (int ni = 0; ni < 4; ++ni)
      wl4[ni] = *(const short8*)(bp + 24576 + offw[ni]);
#pragma unroll
    for (int mi = 0; mi < 8; ++mi)
#pragma unroll
      for (int ni = 0; ni < 4; ++ni)
        acc[mi][ni] = __builtin_amdgcn_mfma_f32_16x16x32_bf16(
            ah[mi], wl4[ni], acc[mi][ni], 0, 0, 0);
    __builtin_amdgcn_s_setprio(0);

    asm volatile("s_waitcnt lgkmcnt(0)" : : : "memory");
    __builtin_amdgcn_sched_barrier(0);
    __builtin_amdgcn_s_barrier();  // buf[ks&1] free to overwrite

    if (ks + 2 < 32) {
#pragma unroll
      for (int s8 = 0; s8 < 8; ++s8)
        gld_lds16(gsrc[s8] + (ks + 2) * 32, &lds2[ks & 1][ldst[s8]]);
      asm volatile("s_waitcnt vmcnt(8)" : : : "memory");
    } else {
      asm volatile("s_waitcnt vmcnt(0)" : : : "memory");
    }
    __builtin_amdgcn_s_barrier();  // buf[(ks+1)&1] ready for all waves
  }

  // epilogue: C/D layout (m89): col = lane&15, row = (lane>>4)*4+reg.
  // window row -> super-chunk row: b*S + toff + m
#pragma unroll
  for (int mi = 0; mi < 8; ++mi)
#pragma unroll
    for (int ni = 0; ni < 4; ++ni)
#pragma unroll
      for (int r = 0; r < 4; ++r) {
        int cr = bx * 256 + wm * 128 + mi * 16 + kg * 4 + r;
        int b = cr >> lw, m = cr & wmask;
        size_t growo = (size_t)b * S + toff + m;
        int gcol = by * 256 + wn * 64 + ni * 16 + l15;
        G[growo * 4096 + gcol] = acc[mi][ni][r];
      }
}

// ---------------- Recurrence (round-12/15 measured-best) -------------------
// Scalar v_fmac matvec on resident weight regs; readlane h-broadcast;
// stride-20 b128 partial exchange; +1-step G prefetch; ONE raw s_barrier
// per step with lgkmcnt(0)-only drain. 0.85us/step measured. Round-16's
// bias-fold into pair-0 partials REGRESSED (lengthened the pre-barrier
// critical path) -> reverted: bias+G applied in the gate phase.
__global__ __launch_bounds__(512, 1)
void recur_kernel(const float* __restrict__ G,     // [32*tch, 4096] chunk
                  const float* __restrict__ Whh,   // [8,512,128]
                  const float* __restrict__ bias,  // [8,512]
                  float* __restrict__ out,         // [32,512,1024]
                  float* __restrict__ state,       // 4 x [32,8,128]
                  int t0, int tch, int first) {
  int blk = blockIdx.x;
  int b = blk >> 3, h = blk & 7;
  int t = threadIdx.x;
  int w = t >> 6;             // wave 0..7
  int l = t & 63;             // lane
  int q = w >> 1;             // col-slice / pair 0..3
  int em = (w & 1) * 64 + l;  // matvec output element 0..127
  int eg = q * 32 + (l & 31); // gate element this thread maintains

  __shared__ __align__(16) float part[2][128 * 20];  // 20 KB

  // weights: wreg[g*32+c] = Whh[h][g*128+em][32q+c]
  float wreg[128];
  {
    const float* wb = Whh + (size_t)h * 65536 + (size_t)q * 32;
#pragma unroll
    for (int g = 0; g < 4; ++g) {
      const float4* wp = (const float4*)(wb + (size_t)(g * 128 + em) * 128);
#pragma unroll
      for (int c4 = 0; c4 < 8; ++c4) {
        float4 v = wp[c4];
        wreg[g * 32 + c4 * 4 + 0] = v.x;
        wreg[g * 32 + c4 * 4 + 1] = v.y;
        wreg[g * 32 + c4 * 4 + 2] = v.z;
        wreg[g * 32 + c4 * 4 + 3] = v.w;
      }
    }
  }
#pragma unroll
  for (int i = 0; i < 128; ++i)
    asm volatile("" : "+v"(wreg[i]));  // opaque def: keep resident

  int si = (b * 8 + h) * 128 + eg;
  float hreg = 0.f, c_r = 0.f, n_r = 0.f, m_r = 0.f;
  if (!first) {
    hreg = state[si];
    c_r = state[32768 + si];
    m_r = state[65536 + si];
    n_r = state[98304 + si];
  }
  float bj0 = bias[h * 512 + eg];
  float bj1 = bias[h * 512 + 128 + eg];
  float bj2 = bias[h * 512 + 256 + eg];
  float bj3 = bias[h * 512 + 384 + eg];

  const float* gpb = G + (size_t)(b * tch) * 4096 + h * 512 + eg;
  float* op = out + ((size_t)b * 512 + t0) * 1024 + h * 128 + eg;
  bool writer = ((w & 1) == 0) && (l < 32);

  int ebase = em * 20 + q * 4;   // write slot
  int rb0 = eg * 20 + 0;
  int rb1 = eg * 20 + 4;
  int rb2 = eg * 20 + 8;
  int rb3 = eg * 20 + 12;

  // G for step 0 (exposed once; later steps prefetched +1 ahead)
  float g0 = gpb[0], g1 = gpb[128], g2 = gpb[256], g3 = gpb[384];

  for (int s = 0; s < tch; ++s) {
    // prefetch G for step s+1 (consumed at END of iteration s+1)
    float gn0 = 0.f, gn1 = 0.f, gn2 = 0.f, gn3 = 0.f;
    if (s + 1 < tch) {
      const float* gr = gpb + (size_t)(s + 1) * 4096;
      gn0 = gr[0]; gn1 = gr[128]; gn2 = gr[256]; gn3 = gr[384];
    }

    // ---- matvec: h broadcast via readlane (VALU), no LDS ----
    float a0 = 0.f, a1 = 0.f, a2 = 0.f, a3 = 0.f;
    int hbits = __float_as_int(hreg);
#pragma unroll
    for (int c = 0; c < 32; ++c) {
      float hs = __int_as_float(__builtin_amdgcn_readlane(hbits, c));
      a0 = fmaf(wreg[c], hs, a0);
      a1 = fmaf(wreg[32 + c], hs, a1);
      a2 = fmaf(wreg[64 + c], hs, a2);
      a3 = fmaf(wreg[96 + c], hs, a3);
    }
    float4 pv = {a0, a1, a2, a3};
    *(float4*)&part[s & 1][ebase] = pv;

    // barrier: only LDS must be visible across it (lgkm), NOT vmem
    asm volatile("s_waitcnt lgkmcnt(0)" : : : "memory");
    __builtin_amdgcn_sched_barrier(0);
    __builtin_amdgcn_s_barrier();

    // ---- gate: all waves, redundant per (lane-half x pair) ----
    float4 p0 = *(const float4*)&part[s & 1][rb0];
    float4 p1 = *(const float4*)&part[s & 1][rb1];
    float4 p2 = *(const float4*)&part[s & 1][rb2];
    float4 p3 = *(const float4*)&part[s & 1][rb3];
    float iv = bj0 + g0 + ((p0.x + p1.x) + (p2.x + p3.x));
    float fv = bj1 + g1 + ((p0.y + p1.y) + (p2.y + p3.y));
    float zv = bj2 + g2 + ((p0.z + p1.z) + (p2.z + p3.z));
    float ov = bj3 + g3 + ((p0.w + p1.w) + (p2.w + p3.w));
    float e2 = __expf(2.f * zv);
    float zt = 1.f - 2.f * __builtin_amdgcn_rcpf(e2 + 1.f);   // tanh
    float og = __builtin_amdgcn_rcpf(1.f + __expf(-ov));      // sigmoid
    float mn = fmaxf(fv + m_r, iv);
    float ie = __expf(iv - mn);
    float fe = __expf(fv + m_r - mn);
    c_r = fe * c_r + ie * zt;
    n_r = fe * n_r + ie;
    m_r = mn;
    float hnew = og * c_r * __builtin_amdgcn_rcpf(n_r);
    hreg = hnew;
    if (writer) op[(size_t)s * 1024] = hnew;
    g0 = gn0; g1 = gn1; g2 = gn2; g3 = gn3;
  }

  if (writer) {
    state[si] = hreg;
    state[32768 + si] = c_r;
    state[65536 + si] = m_r;
    state[98304 + si] = n_r;
  }
}

// ---------------- launch ----------------
extern "C" void kernel_launch(void* const* d_in, const int* in_sizes, int n_in,
                              void* d_out, int out_size, void* d_ws, size_t ws_size,
                              hipStream_t stream) {
  const float* xs   = (const float*)d_in[0];
  const float* wif  = (const float*)d_in[1];
  const float* wzo  = (const float*)d_in[2];
  const float* whh  = (const float*)d_in[3];
  const float* bias = (const float*)d_in[4];
  float* out = (float*)d_out;

  char* ws = (char*)d_ws;
  unsigned short* Ahi = (unsigned short*)ws;                 // 33,554,432 B
  unsigned short* Alo = (unsigned short*)(ws + 33554432);    // 33,554,432 B
  unsigned short* Whi = (unsigned short*)(ws + 67108864);    //  8,388,608 B
  unsigned short* Wlo = (unsigned short*)(ws + 75497472);    //  8,388,608 B
  const size_t gbase = 83886080;

  // Decoupled chunking (measured optima):
  //   gemm window W = 128 steps  -> L3-resident working set (73.5us best)
  //   recur super-chunk S = 256  -> fewer recur dispatches
  int S = 256;
  while (S > 8 && gbase + (size_t)32 * S * 4096 * 4 + 524288 > ws_size)
    S >>= 1;
  int W = (S < 128) ? S : 128;
  int lw = 0;
  while ((1 << (lw + 1)) <= W) ++lw;

  float* G = (float*)(ws + gbase);
  float* state = (float*)(ws + gbase + (size_t)32 * S * 4096 * 4);

  conv_all<<<20480, 256, 0, stream>>>(xs, wif, wzo, Ahi, Alo, Whi, Wlo);

  for (int t0 = 0; t0 < 512; t0 += S) {
    for (int tw = 0; tw < S; tw += W)
      gemm3_kernel<<<dim3((32 * W) / 256, 16), 512, 0, stream>>>(
          Ahi, Alo, Whi, Wlo, G, t0 + tw, tw, S, lw);
    recur_kernel<<<256, 512, 0, stream>>>(G, whh, bias, out, state, t0, S,
                                          t0 == 0);
  }
}